// Round 10
// baseline (994.328 us; speedup 1.0000x reference)
//
#include <hip/hip_runtime.h>
#include <math.h>

#define NTOK 65536   // B*T = 8*8192
#define T_   8192
#define C_   512

typedef short short8 __attribute__((ext_vector_type(8)));
typedef float f32x4  __attribute__((ext_vector_type(4)));

#define GLDS(gp, lp) __builtin_amdgcn_global_load_lds( \
    (__attribute__((address_space(1))) void*)(void*)(gp), \
    (__attribute__((address_space(3))) void*)(lp), 16, 0, 0)

__device__ __forceinline__ unsigned short f2bf(float f){
  unsigned x = __float_as_uint(f);
  x += 0x7fffu + ((x >> 16) & 1u);
  return (unsigned short)(x >> 16);
}
__device__ __forceinline__ float bflo(unsigned p){ return __uint_as_float(p << 16); }
__device__ __forceinline__ float bfhi(unsigned p){ return __uint_as_float(p & 0xffff0000u); }
__device__ __forceinline__ float bfs(unsigned short u){ return __uint_as_float(((unsigned)u) << 16); }
__device__ __forceinline__ unsigned pack2(float a, float b){
  return (unsigned)f2bf(a) | ((unsigned)f2bf(b) << 16);
}
// bijective XCD chunking (m204)
__device__ __forceinline__ int xcd_remap(int flat, int nwg){
  int q = nwg >> 3, r = nwg & 7;
  int xcd = flat & 7, idx = flat >> 3;
  return (xcd < r ? xcd * (q + 1) : r * (q + 1) + (xcd - r) * q) + idx;
}

// ---------------- weight prep ----------------
__global__ __launch_bounds__(256) void k_convert(const float* __restrict__ src,
                                                 unsigned short* __restrict__ dst, int n){
  int i = blockIdx.x * 256 + threadIdx.x;
  if (i < n) dst[i] = f2bf(src[i]);
}
__global__ __launch_bounds__(256) void k_transpose_t(const float* __restrict__ src,
                                                     unsigned short* __restrict__ dst,
                                                     int R, int S){
  __shared__ float tile[64][65];
  int ntS = S >> 6;
  int tr = blockIdx.x / ntS, ts = blockIdx.x - tr * ntS;
  int tx = threadIdx.x & 63, tg = threadIdx.x >> 6;
  #pragma unroll
  for (int rr = tg; rr < 64; rr += 4)
    tile[rr][tx] = src[(size_t)(tr * 64 + rr) * S + ts * 64 + tx];
  __syncthreads();
  #pragma unroll
  for (int rr = tg; rr < 64; rr += 4)
    dst[(size_t)(ts * 64 + rr) * R + tr * 64 + tx] = f2bf(tile[tx][rr]);
}

// ---------------- layernorm: one block per row (C=512) ----------------
__global__ __launch_bounds__(256) void k_ln(const float* __restrict__ x,
                                            const float* __restrict__ g,
                                            const float* __restrict__ b,
                                            unsigned* __restrict__ outbf){
  int row = blockIdx.x;
  int t = threadIdx.x;
  float2 v = ((const float2*)(x + (size_t)row * C_))[t];
  float s = v.x + v.y, ss = v.x * v.x + v.y * v.y;
  #pragma unroll
  for (int o = 32; o; o >>= 1){ s += __shfl_down(s, o); ss += __shfl_down(ss, o); }
  __shared__ float red[8];
  if ((t & 63) == 0){ red[t >> 6] = s; red[4 + (t >> 6)] = ss; }
  __syncthreads();
  float S = red[0] + red[1] + red[2] + red[3];
  float Q = red[4] + red[5] + red[6] + red[7];
  float mu  = S * (1.0f / C_);
  float var = Q * (1.0f / C_) - mu * mu;
  float rs = rsqrtf(var + 1e-5f);
  float y0 = (v.x - mu) * rs * g[2*t]   + b[2*t];
  float y1 = (v.y - mu) * rs * g[2*t+1] + b[2*t+1];
  outbf[(size_t)row * 256 + t] = pack2(y0, y1);
}

// ---------------- depthwise causal conv K=3, coalesced, chunk-local out ----------------
__global__ __launch_bounds__(256) void k_conv(const unsigned* __restrict__ xn,
                                              const float* __restrict__ w,
                                              const float* __restrict__ bias,
                                              unsigned* __restrict__ loc,
                                              int base){
  size_t idx = (size_t)blockIdx.x * 256 + threadIdx.x;
  size_t n = (idx >> 8) + (size_t)base;
  int cp = (int)(idx & 255);
  int t = (int)(n & (T_ - 1));
  unsigned v0 = xn[n * 256 + cp];
  unsigned v1 = (t >= 1) ? xn[(n - 1) * 256 + cp] : 0u;
  unsigned v2 = (t >= 2) ? xn[(n - 2) * 256 + cp] : 0u;
  int c = cp * 2;
  float r0 = bias[c]     + bflo(v0)*w[c*3+2] + bflo(v1)*w[c*3+1] + bflo(v2)*w[c*3+0];
  float r1 = bias[c + 1] + bfhi(v0)*w[c*3+5] + bfhi(v1)*w[c*3+4] + bfhi(v2)*w[c*3+3];
  loc[idx] = pack2(r0, r1);
}

// ---------------- in-place row softmax over M=512, bf16 ----------------
__global__ __launch_bounds__(256) void k_softmax_ip(unsigned* __restrict__ sw){
  int row = blockIdx.x;
  int t = threadIdx.x;
  unsigned p = sw[(size_t)row * 256 + t];
  float vx = bflo(p), vy = bfhi(p);
  float mx = fmaxf(vx, vy);
  #pragma unroll
  for (int o = 32; o; o >>= 1) mx = fmaxf(mx, __shfl_xor(mx, o));
  __shared__ float red[8];
  int w = t >> 6;
  if ((t & 63) == 0) red[w] = mx;
  __syncthreads();
  mx = fmaxf(fmaxf(red[0], red[1]), fmaxf(red[2], red[3]));
  float e0 = __expf(vx - mx), e1 = __expf(vy - mx);
  float s = e0 + e1;
  #pragma unroll
  for (int o = 32; o; o >>= 1) s += __shfl_xor(s, o);
  if ((t & 63) == 0) red[4 + w] = s;
  __syncthreads();
  float inv = 1.0f / (red[4] + red[5] + red[6] + red[7]);
  sw[(size_t)row * 256 + t] = pack2(e0 * inv, e1 * inv);
}

#define PH_PRE  { __builtin_amdgcn_s_barrier(); \
                  asm volatile("s_waitcnt lgkmcnt(0)" ::: "memory"); \
                  __builtin_amdgcn_sched_barrier(0); }
#define PH_END  __builtin_amdgcn_s_barrier();
#define VMW3    asm volatile("s_waitcnt vmcnt(3)" ::: "memory");
#define VMW0    asm volatile("s_waitcnt vmcnt(0)" ::: "memory");

// ============ 128x64 bf16 GEMM, BK=64, 3-buffer depth-2 counted-vmcnt, 2 blk/CU ============
// A: M x K bf16 row-major, Bt: N x K bf16 (B^T). 512 thr = 8 waves (4M x 2N, wave 32x32).
// LDS 72KB: buf b at b*24576 { A[128][64] 16KB | B[64][64] 8KB }. T2 swizzle both sides.
// Schedule (race-free by construction):
//   phase t: RD(buf t%3); stage tile t+2 -> buf (t+2)%3 [3 GLDS]; BAR; lgkm(0); MM;
//            VMW3 (own stages fly, phase t-1 stages landed); BAR.
// WAR: buf (t+2)%3 was read in phase t-1; all waves crossed PH_END(t-1) (reads done via
// lgkm(0)) before any wave issues phase t stages. RAW: at phase t's VMW3 the only flying
// loads are phase t's own 3 -> tile t+1 (staged phase t-1) landed before phase t+1 reads.
// Prologue: stage t0->buf0, t1->buf1 (6 loads); VMW3 -> t0 landed; BAR. Tail: phase nt-2
// has no stage -> VMW0 drains tile nt-1. Depth-2 gives staged loads ~1.5 phases to land.
template<int EPI, int K, int N>
__global__ __launch_bounds__(512, 4) void k_gemm64(const unsigned short* __restrict__ A,
                                                   const unsigned short* __restrict__ Bt,
                                                   void* __restrict__ out,
                                                   const float* __restrict__ bias,
                                                   const float* __restrict__ add){
  __shared__ char smem[73728];
  const int tid  = threadIdx.x;
  const int lane = tid & 63;
  const int w    = tid >> 6;
  const int wr   = w >> 1, wc = w & 1;      // 4M x 2N waves; wave tile 32 x 32
  const int gx   = gridDim.x;
  const int nwg  = gx * gridDim.y;
  const int wgid = xcd_remap(blockIdx.y * gx + blockIdx.x, nwg);
  const long bcol = (long)(wgid % gx) * 64;
  const long brow = (long)(wgid / gx) * 128;
  const int lr = lane & 15;
  const int lk = (lane >> 4) * 16;
  const int srow  = tid >> 3;                               // 0..63 (8 thr/row)
  const int sbyte = ((tid & 7) * 16) ^ ((srow & 7) << 4);   // T2 pre-swizzled src col
  const unsigned swb = (unsigned)(w * 1024);
  const int rsw = (lr & 7) << 4;                            // T2 read-side XOR

  f32x4 acc[2][2];
  #pragma unroll
  for (int i = 0; i < 2; i++)
    #pragma unroll
    for (int j = 0; j < 2; j++){ f32x4 z = {0.f,0.f,0.f,0.f}; acc[i][j] = z; }

  const char* Ab = (const char*)(A + brow * (long)K);
  const char* Bb = (const char*)(Bt + bcol * (long)K);

  auto ST = [&](const char* g, int ldsoff, int row0, int kt){
    GLDS(g + ((long)(row0 + srow) * K + (long)kt * 64) * 2 + sbyte,
         smem + ldsoff + row0 * 128 + swb);
  };
  // one tile = 3 GLDS: A rows 0-63, A rows 64-127, B rows 0-63
  auto stT = [&](int b, int kt){
    ST(Ab, b*24576, 0, kt); ST(Ab, b*24576, 64, kt); ST(Bb, b*24576+16384, 0, kt);
  };

  short8 afr[2][2], bfr[2][2];
  auto RD = [&](int b){
    #pragma unroll
    for (int mi = 0; mi < 2; mi++)
      #pragma unroll
      for (int kk = 0; kk < 2; kk++)
        afr[mi][kk] = *(const short8*)(smem + b*24576 +
            (wr*32 + mi*16 + lr) * 128 + ((kk*64 + lk) ^ rsw));
    #pragma unroll
    for (int ni = 0; ni < 2; ni++)
      #pragma unroll
      for (int kk = 0; kk < 2; kk++)
        bfr[ni][kk] = *(const short8*)(smem + b*24576 + 16384 +
            (wc*32 + ni*16 + lr) * 128 + ((kk*64 + lk) ^ rsw));
  };
  auto MM = [&](){
    __builtin_amdgcn_s_setprio(1);
    #pragma unroll
    for (int mi = 0; mi < 2; mi++)
      #pragma unroll
      for (int ni = 0; ni < 2; ni++)
        #pragma unroll
        for (int kk = 0; kk < 2; kk++)
          acc[mi][ni] = __builtin_amdgcn_mfma_f32_16x16x32_bf16(afr[mi][kk], bfr[ni][kk],
                                                                acc[mi][ni], 0, 0, 0);
    __builtin_amdgcn_s_setprio(0);
  };

  constexpr int nt = K >> 6;   // >= 2

  // prologue: tiles 0,1 -> bufs 0,1
  stT(0, 0); stT(1, 1);
  VMW3;                          // 6 outstanding -> wait to 3: tile0 landed (all waves at BAR)
  __builtin_amdgcn_s_barrier();

  int b = 0, bs = 2;             // compute buf, stage buf
  #pragma unroll 1
  for (int t = 0; t < nt; t++){
    RD(b);
    if (t + 2 < nt) stT(bs, t + 2);
    PH_PRE; MM();
    if (t + 2 < nt)      { VMW3; }
    else if (t + 1 < nt) { VMW0; }
    PH_END;
    b  = (b  == 2) ? 0 : b  + 1;
    bs = (bs == 2) ? 0 : bs + 1;
  }

  // epilogue: C/D layout col=lane&15, row=(lane>>4)*4+j
  const long rb = brow + wr * 32;
  const long cb = bcol + wc * 32;
  #pragma unroll
  for (int mi = 0; mi < 2; mi++){
    #pragma unroll
    for (int ni = 0; ni < 2; ni++){
      long rg0 = rb + mi * 16 + (lane >> 4) * 4;
      long cg  = cb + ni * 16 + lr;
      #pragma unroll
      for (int j = 0; j < 4; j++){
        long oi = (rg0 + j) * (long)N + cg;
        float v = acc[mi][ni][j];
        if (EPI == 1){
          ((unsigned short*)out)[oi] = f2bf(v);
        } else if (EPI == 3){
          v += bias[cg];
          v = 0.5f * v * (1.0f + erff(v * 0.70710678118654752f));
          ((unsigned short*)out)[oi] = f2bf(v);
        } else {
          v += bias[cg] + add[oi];
          ((float*)out)[oi] = v;
        }
      }
    }
  }
}

// ===== fused gates GEMM + sigmoid + combine + residual (R9 version, unchanged) =====
__global__ __launch_bounds__(512, 4) void k_gc128(const unsigned short* __restrict__ A,
                                                  const unsigned short* __restrict__ Bt,
                                                  const float* __restrict__ gb,
                                                  const unsigned short* __restrict__ loc,
                                                  const unsigned short* __restrict__ ctx,
                                                  const float* __restrict__ x,
                                                  float* __restrict__ x2){
  __shared__ char smem[65536];
  const int tid  = threadIdx.x;
  const int lane = tid & 63;
  const int w    = tid >> 6;
  const int wr   = w >> 1, wc = w & 1;      // 4M x 2N waves
  const int gx   = gridDim.x;               // 8
  const int nwg  = gx * gridDim.y;
  const int wgid = xcd_remap(blockIdx.y * gx + blockIdx.x, nwg);
  const int  bcol = (wgid % gx) * 64;
  const long brow = (long)(wgid / gx) * 128;
  const int K = 512;
  const int lr = lane & 15;
  const int lk = (lane >> 4) * 16;
  const int srow  = tid >> 3;
  const int sbyte = ((tid & 7) * 16) ^ ((srow & 7) << 4);
  const unsigned swb = (unsigned)(w * 1024);
  const int rsw = (lr & 7) << 4;

  f32x4 acc[2][2][2];   // mi, ni, half
  #pragma unroll
  for (int i = 0; i < 2; i++)
    #pragma unroll
    for (int j = 0; j < 2; j++)
      #pragma unroll
      for (int h = 0; h < 2; h++){ f32x4 z = {0.f,0.f,0.f,0.f}; acc[i][j][h] = z; }

  const char* Ab  = (const char*)(A + brow * (long)K);
  const char* BbL = (const char*)(Bt + (long)bcol * K);
  const char* BbG = (const char*)(Bt + (long)(512 + bcol) * K);

  auto ST = [&](const char* g, int ldsoff, int row0, int kt){
    GLDS(g + ((long)(row0 + srow) * K + (long)kt * 64) * 2 + sbyte,
         smem + ldsoff + row0 * 128 + swb);
  };
  auto stA = [&](int b, int kt){ ST(Ab, b*16384, 0, kt); ST(Ab, b*16384, 64, kt); };
  auto stB = [&](int b, int kt){ ST(BbL, 32768+b*8192, 0, kt); ST(BbG, 49152+b*8192, 0, kt); };

  short8 afr[2][2], blf[2][2], bgf[2][2];
  auto RD = [&](int b){
    #pragma unroll
    for (int mi = 0; mi < 2; mi++)
      #pragma unroll
      for (int kk = 0; kk < 2; kk++)
        afr[mi][kk] = *(const short8*)(smem + b*16384 +
            (wr*32 + mi*16 + lr) * 128 + ((kk*64 + lk) ^ rsw));
    #pragma unroll
    for (int ni = 0; ni < 2; ni++)
      #pragma unroll
      for (int kk = 0; kk < 2; kk++){
        blf[ni][kk] = *(const short8*)(smem + 32768 + b*8192 +
            (wc*32 + ni*16 + lr) * 128 + ((kk*64 + lk) ^ rsw));
        bgf[ni][kk] = *(const short8*)(smem + 49152 + b*8192 +
            (wc*32 + ni*16 + lr) * 128 + ((kk*64 + lk) ^ rsw));
      }
  };
  auto MM = [&](){
    __builtin_amdgcn_s_setprio(1);
    #pragma unroll
    for (int mi = 0; mi < 2; mi++)
      #pragma unroll
      for (int ni = 0; ni < 2; ni++)
        #pragma unroll
        for (int kk = 0; kk < 2; kk++){
          acc[mi][ni][0] = __builtin_amdgcn_mfma_f32_16x16x32_bf16(afr[mi][kk], blf[ni][kk],
                                                                   acc[mi][ni][0], 0, 0, 0);
          acc[mi][ni][1] = __builtin_amdgcn_mfma_f32_16x16x32_bf16(afr[mi][kk], bgf[ni][kk],
                                                                   acc[mi][ni][1], 0, 0, 0);
        }
    __builtin_amdgcn_s_setprio(0);
  };

  constexpr int nt = 8;   // K=512

  stA(0, 0); stB(0, 0);
  VMW0;
  __builtin_amdgcn_s_barrier();

  #pragma unroll 1
  for (int t = 0; t < nt; t++){
    const int b = t & 1;
    RD(b);
    if (t + 1 < nt){ stA(b ^ 1, t + 1); stB(b ^ 1, t + 1); }
    PH_PRE; MM();
    if (t + 1 < nt) { VMW0; }
    PH_END;
  }

  const long rb = brow + wr * 32;
  const int  cb = bcol + wc * 32;
  #pragma unroll
  for (int mi = 0; mi < 2; mi++){
    #pragma unroll
    for (int ni = 0; ni < 2; ni++){
      long rg0 = rb + mi * 16 + (lane >> 4) * 4;
      int  cg  = cb + ni * 16 + lr;
      float bL = gb[cg], bG = gb[512 + cg];
      #pragma unroll
      for (int j = 0; j < 4; j++){
        long rg = rg0 + j;
        long oi = rg * 512 + cg;
        float vL = 1.0f / (1.0f + __expf(-(acc[mi][ni][0][j] + bL)));
        float vG = 1.0f / (1.0f + __expf(-(acc[mi][ni][1][j] + bG)));
        x2[oi] = x[oi] + vL * bfs(loc[oi]) + vG * bfs(ctx[oi]);
      }
    }
  }
}

// ---------------- launch ----------------
extern "C" void kernel_launch(void* const* d_in, const int* in_sizes, int n_in,
                              void* d_out, int out_size, void* d_ws, size_t ws_size,
                              hipStream_t stream){
  const float* x      = (const float*)d_in[0];
  const float* conv_w = (const float*)d_in[1];
  const float* conv_b = (const float*)d_in[2];
  const float* mb     = (const float*)d_in[3];
  const float* gate_w = (const float*)d_in[4];
  const float* gate_b = (const float*)d_in[5];
  const float* w1     = (const float*)d_in[6];
  const float* b1     = (const float*)d_in[7];
  const float* w2     = (const float*)d_in[8];
  const float* b2     = (const float*)d_in[9];
  const float* ln1g   = (const float*)d_in[10];
  const float* ln1b   = (const float*)d_in[11];
  const float* ln2g   = (const float*)d_in[12];
  const float* ln2b   = (const float*)d_in[13];

  char* ws = (char*)d_ws;
  const size_t MB = 1024ull * 1024ull;
  unsigned short* mb_bf = (unsigned short*)(ws + 0);
  unsigned short* mbT   = (unsigned short*)(ws + 512 * 1024);
  unsigned short* gwT   = (unsigned short*)(ws + 1 * MB);
  unsigned short* w1T   = (unsigned short*)(ws + 2 * MB);
  unsigned short* w2T   = (unsigned short*)(ws + 4 * MB);
  unsigned short* xn    = (unsigned short*)(ws + 8 * MB);   // 64MB; reused as h
  char* region = ws + 72 * MB;

  int S;
  if      (ws_size >= 264 * MB) S = 65536;
  else if (ws_size >= 120 * MB) S = 16384;
  else                          S = 4096;
  const int S2 = S / 2;
  const int NC  = NTOK / S;
  const int NC2 = NTOK / S2;

  unsigned short* loc_c = (unsigned short*)(region);
  unsigned short* ctx_c = (unsigned short*)(region + (size_t)S * 1024);
  unsigned short* sco_c = (unsigned short*)(region + (size_t)S * 2048);
  unsigned short* f1    = (unsigned short*)(region);

  // weight prep
  k_convert    <<<1024, 256, 0, stream>>>(mb, mb_bf, 512 * 512);
  k_transpose_t<<<  64, 256, 0, stream>>>(mb, mbT, 512, 512);
  k_transpose_t<<< 128, 256, 0, stream>>>(gate_w, gwT, 512, 1024);
  k_transpose_t<<< 256, 256, 0, stream>>>(w1, w1T, 512, 2048);
  k_transpose_t<<< 256, 256, 0, stream>>>(w2, w2T, 2048, 512);

  // LN1 -> xn (bf16, full)
  k_ln<<<NTOK, 256, 0, stream>>>(x, ln1g, ln1b, (unsigned*)xn);

  // middle phase, chunked over tokens
  for (int c = 0; c < NC; c++){
    const int base = c * S;
    const unsigned short* xnc = xn + (size_t)base * 512;
    k_conv<<<S, 256, 0, stream>>>((const unsigned*)xn, conv_w, conv_b,
                                  (unsigned*)loc_c, base);
    // scores = xn @ mb^T (bf16)
    k_gemm64<1, 512, 512><<<dim3(8, S / 128), 512, 0, stream>>>(xnc, mb_bf, sco_c,
                                                                nullptr, nullptr);
    k_softmax_ip<<<S, 256, 0, stream>>>((unsigned*)sco_c);
    // ctx = weights @ mb (bf16)
    k_gemm64<1, 512, 512><<<dim3(8, S / 128), 512, 0, stream>>>(sco_c, mbT, ctx_c,
                                                                nullptr, nullptr);
    // gates GEMM + sigmoid + combine + residual -> x2 (f32, into d_out)
    k_gc128<<<dim3(8, S / 128), 512, 0, stream>>>(xnc, gwT, gate_b,
                                                  loc_c, ctx_c,
                                                  x + (size_t)base * 512,
                                                  (float*)d_out + (size_t)base * 512);
  }

  // LN2: h = LN(x2) (bf16, reuse xn buffer)
  k_ln<<<NTOK, 256, 0, stream>>>((const float*)d_out, ln2g, ln2b, (unsigned*)xn);

  // FFN, chunked
  for (int c = 0; c < NC2; c++){
    const int base = c * S2;
    // f1 = gelu(h @ w1 + b1) (bf16)
    k_gemm64<3, 512, 2048><<<dim3(32, S2 / 128), 512, 0, stream>>>(xn + (size_t)base * 512,
                                                                   w1T, f1, b1, nullptr);
    // out = x2 + f1 @ w2 + b2 (f32, in-place per-element on d_out)
    k_gemm64<4, 2048, 512><<<dim3(8, S2 / 128), 512, 0, stream>>>(f1, w2T,
                                                                  (float*)d_out + (size_t)base * 512,
                                                                  b2,
                                                                  (const float*)d_out + (size_t)base * 512);
  }
}

// Round 11
// 879.215 us; speedup vs baseline: 1.1309x; 1.1309x over previous
//
#include <hip/hip_runtime.h>
#include <math.h>

#define NTOK 65536   // B*T = 8*8192
#define T_   8192
#define C_   512

typedef short short8 __attribute__((ext_vector_type(8)));
typedef float f32x4  __attribute__((ext_vector_type(4)));

#define GLDS(gp, lp) __builtin_amdgcn_global_load_lds( \
    (__attribute__((address_space(1))) void*)(void*)(gp), \
    (__attribute__((address_space(3))) void*)(lp), 16, 0, 0)

__device__ __forceinline__ unsigned short f2bf(float f){
  unsigned x = __float_as_uint(f);
  x += 0x7fffu + ((x >> 16) & 1u);
  return (unsigned short)(x >> 16);
}
__device__ __forceinline__ float bflo(unsigned p){ return __uint_as_float(p << 16); }
__device__ __forceinline__ float bfhi(unsigned p){ return __uint_as_float(p & 0xffff0000u); }
__device__ __forceinline__ float bfs(unsigned short u){ return __uint_as_float(((unsigned)u) << 16); }
__device__ __forceinline__ unsigned pack2(float a, float b){
  return (unsigned)f2bf(a) | ((unsigned)f2bf(b) << 16);
}
// bijective XCD chunking (m204)
__device__ __forceinline__ int xcd_remap(int flat, int nwg){
  int q = nwg >> 3, r = nwg & 7;
  int xcd = flat & 7, idx = flat >> 3;
  return (xcd < r ? xcd * (q + 1) : r * (q + 1) + (xcd - r) * q) + idx;
}

// ---------------- fused weight prep: 1 kernel, block-range dispatch ----------------
// blocks [0,64): mb -> mbT | [64,192): gate_w -> gwT | [192,448): w1 -> w1T
// [448,704): w2 -> w2T | [704,1728): mb -> mb_bf convert
__global__ __launch_bounds__(256) void k_prep(const float* __restrict__ mb,
                                              const float* __restrict__ gate_w,
                                              const float* __restrict__ w1,
                                              const float* __restrict__ w2,
                                              unsigned short* __restrict__ mb_bf,
                                              unsigned short* __restrict__ mbT,
                                              unsigned short* __restrict__ gwT,
                                              unsigned short* __restrict__ w1T,
                                              unsigned short* __restrict__ w2T){
  __shared__ float tile[64][65];
  const int bid = blockIdx.x;
  const float* src; unsigned short* dst; int R, S, t0;
  if (bid < 64)       { src = mb;     dst = mbT; R = 512;  S = 512;  t0 = bid; }
  else if (bid < 192) { src = gate_w; dst = gwT; R = 512;  S = 1024; t0 = bid - 64; }
  else if (bid < 448) { src = w1;     dst = w1T; R = 512;  S = 2048; t0 = bid - 192; }
  else if (bid < 704) { src = w2;     dst = w2T; R = 2048; S = 512;  t0 = bid - 448; }
  else {
    int i = (bid - 704) * 256 + threadIdx.x;
    mb_bf[i] = f2bf(mb[i]);
    return;
  }
  int ntS = S >> 6;
  int tr = t0 / ntS, ts = t0 - tr * ntS;
  int tx = threadIdx.x & 63, tg = threadIdx.x >> 6;
  #pragma unroll
  for (int rr = tg; rr < 64; rr += 4)
    tile[rr][tx] = src[(size_t)(tr * 64 + rr) * S + ts * 64 + tx];
  __syncthreads();
  #pragma unroll
  for (int rr = tg; rr < 64; rr += 4)
    dst[(size_t)(ts * 64 + rr) * R + tr * 64 + tx] = f2bf(tile[tx][rr]);
}

// ---------------- layernorm: one block per row (C=512) ----------------
__global__ __launch_bounds__(256) void k_ln(const float* __restrict__ x,
                                            const float* __restrict__ g,
                                            const float* __restrict__ b,
                                            unsigned* __restrict__ outbf){
  int row = blockIdx.x;
  int t = threadIdx.x;
  float2 v = ((const float2*)(x + (size_t)row * C_))[t];
  float s = v.x + v.y, ss = v.x * v.x + v.y * v.y;
  #pragma unroll
  for (int o = 32; o; o >>= 1){ s += __shfl_down(s, o); ss += __shfl_down(ss, o); }
  __shared__ float red[8];
  if ((t & 63) == 0){ red[t >> 6] = s; red[4 + (t >> 6)] = ss; }
  __syncthreads();
  float S = red[0] + red[1] + red[2] + red[3];
  float Q = red[4] + red[5] + red[6] + red[7];
  float mu  = S * (1.0f / C_);
  float var = Q * (1.0f / C_) - mu * mu;
  float rs = rsqrtf(var + 1e-5f);
  float y0 = (v.x - mu) * rs * g[2*t]   + b[2*t];
  float y1 = (v.y - mu) * rs * g[2*t+1] + b[2*t+1];
  outbf[(size_t)row * 256 + t] = pack2(y0, y1);
}

// ---------------- depthwise causal conv K=3, coalesced, chunk-local out ----------------
__global__ __launch_bounds__(256) void k_conv(const unsigned* __restrict__ xn,
                                              const float* __restrict__ w,
                                              const float* __restrict__ bias,
                                              unsigned* __restrict__ loc,
                                              int base){
  size_t idx = (size_t)blockIdx.x * 256 + threadIdx.x;
  size_t n = (idx >> 8) + (size_t)base;
  int cp = (int)(idx & 255);
  int t = (int)(n & (T_ - 1));
  unsigned v0 = xn[n * 256 + cp];
  unsigned v1 = (t >= 1) ? xn[(n - 1) * 256 + cp] : 0u;
  unsigned v2 = (t >= 2) ? xn[(n - 2) * 256 + cp] : 0u;
  int c = cp * 2;
  float r0 = bias[c]     + bflo(v0)*w[c*3+2] + bflo(v1)*w[c*3+1] + bflo(v2)*w[c*3+0];
  float r1 = bias[c + 1] + bfhi(v0)*w[c*3+5] + bfhi(v1)*w[c*3+4] + bfhi(v2)*w[c*3+3];
  loc[idx] = pack2(r0, r1);
}

// ---------------- in-place row softmax over M=512, bf16 ----------------
__global__ __launch_bounds__(256) void k_softmax_ip(unsigned* __restrict__ sw){
  int row = blockIdx.x;
  int t = threadIdx.x;
  unsigned p = sw[(size_t)row * 256 + t];
  float vx = bflo(p), vy = bfhi(p);
  float mx = fmaxf(vx, vy);
  #pragma unroll
  for (int o = 32; o; o >>= 1) mx = fmaxf(mx, __shfl_xor(mx, o));
  __shared__ float red[8];
  int w = t >> 6;
  if ((t & 63) == 0) red[w] = mx;
  __syncthreads();
  mx = fmaxf(fmaxf(red[0], red[1]), fmaxf(red[2], red[3]));
  float e0 = __expf(vx - mx), e1 = __expf(vy - mx);
  float s = e0 + e1;
  #pragma unroll
  for (int o = 32; o; o >>= 1) s += __shfl_xor(s, o);
  if ((t & 63) == 0) red[4 + w] = s;
  __syncthreads();
  float inv = 1.0f / (red[4] + red[5] + red[6] + red[7]);
  sw[(size_t)row * 256 + t] = pack2(e0 * inv, e1 * inv);
}

// =================== 256x256 8-phase bf16 GEMM (T1+T2+T3+T4+T5) — R7-proven ===================
#define PH_PRE  { __builtin_amdgcn_s_barrier(); \
                  asm volatile("s_waitcnt lgkmcnt(0)" ::: "memory"); \
                  __builtin_amdgcn_sched_barrier(0); }
#define PH_END  __builtin_amdgcn_s_barrier();
#define VMW2    asm volatile("s_waitcnt vmcnt(2)" ::: "memory");
#define VMW0    asm volatile("s_waitcnt vmcnt(0)" ::: "memory");

template<int EPI, int K, int N>
__global__ __launch_bounds__(512, 2) void k_g256(const unsigned short* __restrict__ A,
                                                 const unsigned short* __restrict__ Bt,
                                                 void* __restrict__ out,
                                                 const float* __restrict__ bias,
                                                 const float* __restrict__ add){
  __shared__ char smem[131072];
  const int tid  = threadIdx.x;
  const int lane = tid & 63;
  const int w    = tid >> 6;
  const int wr   = w >> 2, wc = w & 3;
  const int nwg  = gridDim.x * gridDim.y;
  const int wgid = xcd_remap(blockIdx.y * gridDim.x + blockIdx.x, nwg);
  const long bcol = (long)(wgid % gridDim.x) * 256;
  const long brow = (long)(wgid / gridDim.x) * 256;
  const int lr = lane & 15;
  const int lk = (lane >> 4) * 16;
  const int srow  = tid >> 3;
  const int sbyte = ((tid & 7) * 16) ^ ((srow & 7) << 4);   // T2 pre-swizzled source col
  const unsigned swb = (unsigned)(w * 1024);
  const int rsw = (lr & 7) << 4;                            // T2 read-side XOR

  f32x4 acc[8][4];
  #pragma unroll
  for (int i = 0; i < 8; i++)
    #pragma unroll
    for (int j = 0; j < 4; j++){ f32x4 z = {0.f,0.f,0.f,0.f}; acc[i][j] = z; }

  const char* Ab = (const char*)(A + brow * (long)K);
  const char* Bb = (const char*)(Bt + bcol * (long)K);

  auto ST = [&](const char* g, int ldsoff, int row0, int kt){
    GLDS(g + ((long)(row0 + srow) * K + (long)kt * 64) * 2 + sbyte,
         smem + ldsoff + row0 * 128 + swb);
  };
  auto stA0 = [&](int b, int kt){ ST(Ab, b*32768, 0,  kt); ST(Ab, b*32768, 128, kt); };
  auto stA1 = [&](int b, int kt){ ST(Ab, b*32768, 64, kt); ST(Ab, b*32768, 192, kt); };
  auto stB0 = [&](int b, int kt){ ST(Bb, 65536+b*32768, 0,   kt); ST(Bb, 65536+b*32768, 64,  kt); };
  auto stB1 = [&](int b, int kt){ ST(Bb, 65536+b*32768, 128, kt); ST(Bb, 65536+b*32768, 192, kt); };

  short8 afr[4][2], bfr[2][2];
  auto RDA = [&](int b, int qm){
    #pragma unroll
    for (int mj = 0; mj < 4; mj++)
      #pragma unroll
      for (int kk = 0; kk < 2; kk++)
        afr[mj][kk] = *(const short8*)(smem + b*32768 +
            (wr*128 + (qm*4+mj)*16 + lr) * 128 + ((kk*64 + lk) ^ rsw));
  };
  auto RDB = [&](int b, int qn){
    #pragma unroll
    for (int nj = 0; nj < 2; nj++)
      #pragma unroll
      for (int kk = 0; kk < 2; kk++)
        bfr[nj][kk] = *(const short8*)(smem + 65536 + b*32768 +
            (wc*64 + (qn*2+nj)*16 + lr) * 128 + ((kk*64 + lk) ^ rsw));
  };
  auto MM = [&](int qm, int qn){
    __builtin_amdgcn_s_setprio(1);
    #pragma unroll
    for (int mj = 0; mj < 4; mj++)
      #pragma unroll
      for (int nj = 0; nj < 2; nj++)
        #pragma unroll
        for (int kk = 0; kk < 2; kk++)
          acc[qm*4+mj][qn*2+nj] =
            __builtin_amdgcn_mfma_f32_16x16x32_bf16(afr[mj][kk], bfr[nj][kk],
                                                    acc[qm*4+mj][qn*2+nj], 0, 0, 0);
    __builtin_amdgcn_s_setprio(0);
  };

  constexpr int nt    = K >> 6;
  constexpr int niter = nt >> 1;

  stA0(0, 0); stA1(0, 0); stB0(0, 0); stB1(0, 0);
  stA0(1, 1);
  VMW2;
  __builtin_amdgcn_s_barrier();

  #pragma unroll 1
  for (int i = 0; i < niter; i++){
    const int t = 2 * i;
    RDA(0,0); RDB(0,0); stA1(1, t+1);
    PH_PRE; MM(0,0); PH_END;
    RDA(0,1); stB0(1, t+1);
    PH_PRE; MM(1,0); PH_END;
    RDA(0,0); RDB(0,1); stB1(1, t+1);
    PH_PRE; MM(0,1); PH_END;
    RDA(0,1); if (t + 2 < nt) stA0(0, t+2);
    PH_PRE; MM(1,1);
    if (t + 2 < nt) { VMW2; } else { VMW0; }
    PH_END;
    RDA(1,0); RDB(1,0); if (t + 2 < nt) stA1(0, t+2);
    PH_PRE; MM(0,0); PH_END;
    RDA(1,1); if (t + 2 < nt) stB0(0, t+2);
    PH_PRE; MM(1,0); PH_END;
    RDA(1,0); RDB(1,1); if (t + 2 < nt) stB1(0, t+2);
    PH_PRE; MM(0,1); PH_END;
    RDA(1,1); if (t + 3 < nt) stA0(1, t+3);
    PH_PRE; MM(1,1);
    if (i + 1 < niter){ if (t + 3 < nt) { VMW2; } else { VMW0; } }
    PH_END;
  }

  const long rb = brow + wr * 128;
  const long cb = bcol + wc * 64;
  #pragma unroll
  for (int mi = 0; mi < 8; mi++){
    #pragma unroll
    for (int ni = 0; ni < 4; ni++){
      long rg0 = rb + mi * 16 + (lane >> 4) * 4;
      long cg  = cb + ni * 16 + lr;
      #pragma unroll
      for (int j = 0; j < 4; j++){
        long oi = (rg0 + j) * (long)N + cg;
        float v = acc[mi][ni][j];
        if (EPI == 1){
          ((unsigned short*)out)[oi] = f2bf(v);
        } else if (EPI == 3){
          v += bias[cg];
          v = 0.5f * v * (1.0f + erff(v * 0.70710678118654752f));
          ((unsigned short*)out)[oi] = f2bf(v);
        } else {
          v += bias[cg] + add[oi];
          ((float*)out)[oi] = v;
        }
      }
    }
  }
}

// ===== fused gates GEMM (8-phase) + sigmoid + gated combine + residual — R7-proven =====
__global__ __launch_bounds__(512, 2) void k_gc256(const unsigned short* __restrict__ A,
                                                  const unsigned short* __restrict__ Bt,
                                                  const float* __restrict__ gb,
                                                  const unsigned short* __restrict__ loc,
                                                  const unsigned short* __restrict__ ctx,
                                                  const float* __restrict__ x,
                                                  float* __restrict__ x2){
  __shared__ char smem[131072];
  const int tid  = threadIdx.x;
  const int lane = tid & 63;
  const int w    = tid >> 6;
  const int wr   = w >> 2, wc = w & 3;
  const int nwg  = gridDim.x * gridDim.y;
  const int wgid = xcd_remap(blockIdx.y * gridDim.x + blockIdx.x, nwg);
  const int  bcol = (wgid % gridDim.x) * 128;
  const long brow = (long)(wgid / gridDim.x) * 256;
  const int K = 512;
  const int lr = lane & 15;
  const int lk = (lane >> 4) * 16;
  const int srow  = tid >> 3;
  const int sbyte = ((tid & 7) * 16) ^ ((srow & 7) << 4);
  const unsigned swb = (unsigned)(w * 1024);
  const int rsw = (lr & 7) << 4;

  f32x4 acc[8][2][2];
  #pragma unroll
  for (int i = 0; i < 8; i++)
    #pragma unroll
    for (int j = 0; j < 2; j++)
      #pragma unroll
      for (int h = 0; h < 2; h++){ f32x4 z = {0.f,0.f,0.f,0.f}; acc[i][j][h] = z; }

  const char* Ab  = (const char*)(A + brow * (long)K);
  const char* BbL = (const char*)(Bt + (long)bcol * K);
  const char* BbG = (const char*)(Bt + (long)(512 + bcol) * K);

  auto ST = [&](const char* g, int ldsoff, int row0, int kt){
    GLDS(g + ((long)(row0 + srow) * K + (long)kt * 64) * 2 + sbyte,
         smem + ldsoff + row0 * 128 + swb);
  };
  auto stA0 = [&](int b, int kt){ ST(Ab, b*32768, 0,  kt); ST(Ab, b*32768, 128, kt); };
  auto stA1 = [&](int b, int kt){ ST(Ab, b*32768, 64, kt); ST(Ab, b*32768, 192, kt); };
  auto stBL = [&](int b, int kt){ ST(BbL, 65536+b*32768,       0, kt); ST(BbL, 65536+b*32768,       64, kt); };
  auto stBG = [&](int b, int kt){ ST(BbG, 65536+b*32768+16384, 0, kt); ST(BbG, 65536+b*32768+16384, 64, kt); };

  short8 afr[4][2], bfr[2][2];
  auto RDA = [&](int b, int qm){
    #pragma unroll
    for (int mj = 0; mj < 4; mj++)
      #pragma unroll
      for (int kk = 0; kk < 2; kk++)
        afr[mj][kk] = *(const short8*)(smem + b*32768 +
            (wr*128 + (qm*4+mj)*16 + lr) * 128 + ((kk*64 + lk) ^ rsw));
  };
  auto RDB = [&](int b, int h){
    #pragma unroll
    for (int nj = 0; nj < 2; nj++)
      #pragma unroll
      for (int kk = 0; kk < 2; kk++)
        bfr[nj][kk] = *(const short8*)(smem + 65536 + b*32768 + h*16384 +
            (wc*32 + nj*16 + lr) * 128 + ((kk*64 + lk) ^ rsw));
  };
  auto MM = [&](int qm, int h){
    __builtin_amdgcn_s_setprio(1);
    #pragma unroll
    for (int mj = 0; mj < 4; mj++)
      #pragma unroll
      for (int nj = 0; nj < 2; nj++)
        #pragma unroll
        for (int kk = 0; kk < 2; kk++)
          acc[qm*4+mj][nj][h] =
            __builtin_amdgcn_mfma_f32_16x16x32_bf16(afr[mj][kk], bfr[nj][kk],
                                                    acc[qm*4+mj][nj][h], 0, 0, 0);
    __builtin_amdgcn_s_setprio(0);
  };

  constexpr int nt = 8, niter = 4;   // K=512

  stA0(0, 0); stA1(0, 0); stBL(0, 0); stBG(0, 0);
  stA0(1, 1);
  VMW2;
  __builtin_amdgcn_s_barrier();

  #pragma unroll 1
  for (int i = 0; i < niter; i++){
    const int t = 2 * i;
    RDA(0,0); RDB(0,0); stA1(1, t+1);
    PH_PRE; MM(0,0); PH_END;
    RDA(0,1); stBL(1, t+1);
    PH_PRE; MM(1,0); PH_END;
    RDA(0,0); RDB(0,1); stBG(1, t+1);
    PH_PRE; MM(0,1); PH_END;
    RDA(0,1); if (t + 2 < nt) stA0(0, t+2);
    PH_PRE; MM(1,1);
    if (t + 2 < nt) { VMW2; } else { VMW0; }
    PH_END;
    RDA(1,0); RDB(1,0); if (t + 2 < nt) stA1(0, t+2);
    PH_PRE; MM(0,0); PH_END;
    RDA(1,1); if (t + 2 < nt) stBL(0, t+2);
    PH_PRE; MM(1,0); PH_END;
    RDA(1,0); RDB(1,1); if (t + 2 < nt) stBG(0, t+2);
    PH_PRE; MM(0,1); PH_END;
    RDA(1,1); if (t + 3 < nt) stA0(1, t+3);
    PH_PRE; MM(1,1);
    if (i + 1 < niter){ if (t + 3 < nt) { VMW2; } else { VMW0; } }
    PH_END;
  }

  const long rbase = brow + wr * 128;
  const int  cb_   = bcol + wc * 32;
  #pragma unroll
  for (int mi = 0; mi < 8; mi++){
    #pragma unroll
    for (int ni = 0; ni < 2; ni++){
      long rg0 = rbase + mi * 16 + (lane >> 4) * 4;
      int  cg  = cb_ + ni * 16 + lr;
      float bL = gb[cg], bG = gb[512 + cg];
      #pragma unroll
      for (int j = 0; j < 4; j++){
        long rg = rg0 + j;
        long oi = rg * 512 + cg;
        float vL = 1.0f / (1.0f + __expf(-(acc[mi][ni][0][j] + bL)));
        float vG = 1.0f / (1.0f + __expf(-(acc[mi][ni][1][j] + bG)));
        x2[oi] = x[oi] + vL * bfs(loc[oi]) + vG * bfs(ctx[oi]);
      }
    }
  }
}

// ---------------- launch ----------------
extern "C" void kernel_launch(void* const* d_in, const int* in_sizes, int n_in,
                              void* d_out, int out_size, void* d_ws, size_t ws_size,
                              hipStream_t stream){
  const float* x      = (const float*)d_in[0];
  const float* conv_w = (const float*)d_in[1];
  const float* conv_b = (const float*)d_in[2];
  const float* mb     = (const float*)d_in[3];
  const float* gate_w = (const float*)d_in[4];
  const float* gate_b = (const float*)d_in[5];
  const float* w1     = (const float*)d_in[6];
  const float* b1     = (const float*)d_in[7];
  const float* w2     = (const float*)d_in[8];
  const float* b2     = (const float*)d_in[9];
  const float* ln1g   = (const float*)d_in[10];
  const float* ln1b   = (const float*)d_in[11];
  const float* ln2g   = (const float*)d_in[12];
  const float* ln2b   = (const float*)d_in[13];

  char* ws = (char*)d_ws;
  const size_t MB = 1024ull * 1024ull;
  unsigned short* mb_bf = (unsigned short*)(ws + 0);
  unsigned short* mbT   = (unsigned short*)(ws + 512 * 1024);
  unsigned short* gwT   = (unsigned short*)(ws + 1 * MB);
  unsigned short* w1T   = (unsigned short*)(ws + 2 * MB);
  unsigned short* w2T   = (unsigned short*)(ws + 4 * MB);
  unsigned short* xn    = (unsigned short*)(ws + 8 * MB);   // 64MB; reused as h
  char* region = ws + 72 * MB;

  int S;
  if      (ws_size >= 264 * MB) S = 65536;
  else if (ws_size >= 120 * MB) S = 16384;
  else                          S = 4096;
  const int S2 = S / 2;
  const int NC  = NTOK / S;
  const int NC2 = NTOK / S2;

  unsigned short* loc_c = (unsigned short*)(region);
  unsigned short* ctx_c = (unsigned short*)(region + (size_t)S * 1024);
  unsigned short* sco_c = (unsigned short*)(region + (size_t)S * 2048);
  unsigned short* f1    = (unsigned short*)(region);

  // fused weight prep (1 kernel)
  k_prep<<<1728, 256, 0, stream>>>(mb, gate_w, w1, w2, mb_bf, mbT, gwT, w1T, w2T);

  // LN1 -> xn (bf16, full)
  k_ln<<<NTOK, 256, 0, stream>>>(x, ln1g, ln1b, (unsigned*)xn);

  // middle phase, chunked over tokens
  for (int c = 0; c < NC; c++){
    const int base = c * S;
    const unsigned short* xnc = xn + (size_t)base * 512;
    k_conv<<<S, 256, 0, stream>>>((const unsigned*)xn, conv_w, conv_b,
                                  (unsigned*)loc_c, base);
    // scores = xn @ mb^T (bf16)
    k_g256<1, 512, 512><<<dim3(2, S / 256), 512, 0, stream>>>(xnc, mb_bf, sco_c,
                                                              nullptr, nullptr);
    k_softmax_ip<<<S, 256, 0, stream>>>((unsigned*)sco_c);
    // ctx = weights @ mb (bf16)
    k_g256<1, 512, 512><<<dim3(2, S / 256), 512, 0, stream>>>(sco_c, mbT, ctx_c,
                                                              nullptr, nullptr);
    // gates GEMM (8-phase) + sigmoid + combine + residual -> x2 (f32, into d_out)
    k_gc256<<<dim3(4, S / 256), 512, 0, stream>>>(xnc, gwT, gate_b,
                                                  loc_c, ctx_c,
                                                  x + (size_t)base * 512,
                                                  (float*)d_out + (size_t)base * 512);
  }

  // LN2: h = LN(x2) (bf16, reuse xn buffer)
  k_ln<<<NTOK, 256, 0, stream>>>((const float*)d_out, ln2g, ln2b, (unsigned*)xn);

  // FFN, chunked
  for (int c = 0; c < NC2; c++){
    const int base = c * S2;
    // f1 = gelu(h @ w1 + b1) (bf16)
    k_g256<3, 512, 2048><<<dim3(8, S2 / 256), 512, 0, stream>>>(xn + (size_t)base * 512,
                                                                w1T, f1, b1, nullptr);
    // out = x2 + f1 @ w2 + b2 (f32, in-place per-element on d_out)
    k_g256<4, 2048, 512><<<dim3(2, S2 / 256), 512, 0, stream>>>(f1, w2T,
                                                                (float*)d_out + (size_t)base * 512,
                                                                b2,
                                                                (const float*)d_out + (size_t)base * 512);
  }
}

// Round 12
// 784.773 us; speedup vs baseline: 1.2670x; 1.1203x over previous
//
#include <hip/hip_runtime.h>
#include <math.h>

#define NTOK 65536   // B*T = 8*8192
#define T_   8192
#define C_   512

typedef short short8 __attribute__((ext_vector_type(8)));
typedef float f32x4  __attribute__((ext_vector_type(4)));

#define GLDS(gp, lp) __builtin_amdgcn_global_load_lds( \
    (__attribute__((address_space(1))) void*)(void*)(gp), \
    (__attribute__((address_space(3))) void*)(lp), 16, 0, 0)

__device__ __forceinline__ unsigned short f2bf(float f){
  unsigned x = __float_as_uint(f);
  x += 0x7fffu + ((x >> 16) & 1u);
  return (unsigned short)(x >> 16);
}
__device__ __forceinline__ float bflo(unsigned p){ return __uint_as_float(p << 16); }
__device__ __forceinline__ float bfhi(unsigned p){ return __uint_as_float(p & 0xffff0000u); }
__device__ __forceinline__ float bfs(unsigned short u){ return __uint_as_float(((unsigned)u) << 16); }
__device__ __forceinline__ unsigned pack2(float a, float b){
  return (unsigned)f2bf(a) | ((unsigned)f2bf(b) << 16);
}
// bijective XCD chunking (m204)
__device__ __forceinline__ int xcd_remap(int flat, int nwg){
  int q = nwg >> 3, r = nwg & 7;
  int xcd = flat & 7, idx = flat >> 3;
  return (xcd < r ? xcd * (q + 1) : r * (q + 1) + (xcd - r) * q) + idx;
}

// ---------------- fused weight prep: 1 kernel, block-range dispatch ----------------
__global__ __launch_bounds__(256) void k_prep(const float* __restrict__ mb,
                                              const float* __restrict__ gate_w,
                                              const float* __restrict__ w1,
                                              const float* __restrict__ w2,
                                              unsigned short* __restrict__ mb_bf,
                                              unsigned short* __restrict__ mbT,
                                              unsigned short* __restrict__ gwT,
                                              unsigned short* __restrict__ w1T,
                                              unsigned short* __restrict__ w2T){
  __shared__ float tile[64][65];
  const int bid = blockIdx.x;
  const float* src; unsigned short* dst; int R, S, t0;
  if (bid < 64)       { src = mb;     dst = mbT; R = 512;  S = 512;  t0 = bid; }
  else if (bid < 192) { src = gate_w; dst = gwT; R = 512;  S = 1024; t0 = bid - 64; }
  else if (bid < 448) { src = w1;     dst = w1T; R = 512;  S = 2048; t0 = bid - 192; }
  else if (bid < 704) { src = w2;     dst = w2T; R = 2048; S = 512;  t0 = bid - 448; }
  else {
    int i = (bid - 704) * 256 + threadIdx.x;
    mb_bf[i] = f2bf(mb[i]);
    return;
  }
  int ntS = S >> 6;
  int tr = t0 / ntS, ts = t0 - tr * ntS;
  int tx = threadIdx.x & 63, tg = threadIdx.x >> 6;
  #pragma unroll
  for (int rr = tg; rr < 64; rr += 4)
    tile[rr][tx] = src[(size_t)(tr * 64 + rr) * S + ts * 64 + tx];
  __syncthreads();
  #pragma unroll
  for (int rr = tg; rr < 64; rr += 4)
    dst[(size_t)(ts * 64 + rr) * R + tr * 64 + tx] = f2bf(tile[tx][rr]);
}

// -------- layernorm: one row per WAVE (4 rows/block), shuffle-only reduce --------
__global__ __launch_bounds__(256) void k_ln4(const float* __restrict__ x,
                                             const float* __restrict__ g,
                                             const float* __restrict__ b,
                                             unsigned* __restrict__ outbf){
  const int row  = blockIdx.x * 4 + (threadIdx.x >> 6);
  const int lane = threadIdx.x & 63;
  const float4* xr = (const float4*)(x + (size_t)row * C_) + lane * 2;
  float4 v0 = xr[0], v1 = xr[1];
  float s  = v0.x + v0.y + v0.z + v0.w + v1.x + v1.y + v1.z + v1.w;
  float ss = v0.x*v0.x + v0.y*v0.y + v0.z*v0.z + v0.w*v0.w
           + v1.x*v1.x + v1.y*v1.y + v1.z*v1.z + v1.w*v1.w;
  #pragma unroll
  for (int o = 32; o; o >>= 1){ s += __shfl_xor(s, o); ss += __shfl_xor(ss, o); }
  float mu  = s * (1.0f / C_);
  float var = ss * (1.0f / C_) - mu * mu;
  float rs = rsqrtf(var + 1e-5f);
  const float4* gr = (const float4*)g + lane * 2;
  const float4* br = (const float4*)b + lane * 2;
  float4 g0 = gr[0], g1 = gr[1], b0 = br[0], b1 = br[1];
  uint4 o4;
  o4.x = pack2((v0.x - mu) * rs * g0.x + b0.x, (v0.y - mu) * rs * g0.y + b0.y);
  o4.y = pack2((v0.z - mu) * rs * g0.z + b0.z, (v0.w - mu) * rs * g0.w + b0.w);
  o4.z = pack2((v1.x - mu) * rs * g1.x + b1.x, (v1.y - mu) * rs * g1.y + b1.y);
  o4.w = pack2((v1.z - mu) * rs * g1.z + b1.z, (v1.w - mu) * rs * g1.w + b1.w);
  ((uint4*)(outbf + (size_t)row * 256))[lane] = o4;
}

// ---- depthwise causal conv K=3: 8 consecutive tokens per thread (traffic 2.4x cut) ----
__global__ __launch_bounds__(256) void k_conv8(const unsigned* __restrict__ xn,
                                               const float* __restrict__ w,
                                               const float* __restrict__ bias,
                                               unsigned* __restrict__ loc,
                                               int base){
  const int cp = threadIdx.x;                 // channel pair 0..255
  const size_t n0 = (size_t)blockIdx.x * 8 + (size_t)base;   // first token (8-aligned)
  const int t0 = (int)(n0 & (T_ - 1));
  const int c = cp * 2;
  const float w00 = w[c*3], w01 = w[c*3+1], w02 = w[c*3+2];
  const float w10 = w[c*3+3], w11 = w[c*3+4], w12 = w[c*3+5];
  const float b0 = bias[c], b1 = bias[c+1];
  unsigned vm2 = (t0 >= 2) ? xn[(n0 - 2) * 256 + cp] : 0u;
  unsigned vm1 = (t0 >= 1) ? xn[(n0 - 1) * 256 + cp] : 0u;
  size_t obase = (n0 - (size_t)base) * 256 + cp;
  #pragma unroll
  for (int k = 0; k < 8; k++){
    unsigned v = xn[(n0 + k) * 256 + cp];
    float r0 = b0 + bflo(v)*w02 + bflo(vm1)*w01 + bflo(vm2)*w00;
    float r1 = b1 + bfhi(v)*w12 + bfhi(vm1)*w11 + bfhi(vm2)*w10;
    loc[obase + (size_t)k * 256] = pack2(r0, r1);
    vm2 = vm1; vm1 = v;
  }
}

// -------- in-place row softmax over M=512: one row per WAVE, shuffle-only --------
__global__ __launch_bounds__(256) void k_softmax4(unsigned* __restrict__ sw){
  const int row  = blockIdx.x * 4 + (threadIdx.x >> 6);
  const int lane = threadIdx.x & 63;
  uint4 p = ((uint4*)(sw + (size_t)row * 256))[lane];
  float v[8];
  v[0]=bflo(p.x); v[1]=bfhi(p.x); v[2]=bflo(p.y); v[3]=bfhi(p.y);
  v[4]=bflo(p.z); v[5]=bfhi(p.z); v[6]=bflo(p.w); v[7]=bfhi(p.w);
  float mx = v[0];
  #pragma unroll
  for (int k = 1; k < 8; k++) mx = fmaxf(mx, v[k]);
  #pragma unroll
  for (int o = 32; o; o >>= 1) mx = fmaxf(mx, __shfl_xor(mx, o));
  float s = 0.f;
  #pragma unroll
  for (int k = 0; k < 8; k++){ v[k] = __expf(v[k] - mx); s += v[k]; }
  #pragma unroll
  for (int o = 32; o; o >>= 1) s += __shfl_xor(s, o);
  float inv = 1.0f / s;
  p.x = pack2(v[0]*inv, v[1]*inv); p.y = pack2(v[2]*inv, v[3]*inv);
  p.z = pack2(v[4]*inv, v[5]*inv); p.w = pack2(v[6]*inv, v[7]*inv);
  ((uint4*)(sw + (size_t)row * 256))[lane] = p;
}

// =================== 256x256 8-phase bf16 GEMM (T1+T2+T3+T4+T5) — R7-proven ===================
#define PH_PRE  { __builtin_amdgcn_s_barrier(); \
                  asm volatile("s_waitcnt lgkmcnt(0)" ::: "memory"); \
                  __builtin_amdgcn_sched_barrier(0); }
#define PH_END  __builtin_amdgcn_s_barrier();
#define VMW2    asm volatile("s_waitcnt vmcnt(2)" ::: "memory");
#define VMW0    asm volatile("s_waitcnt vmcnt(0)" ::: "memory");

template<int EPI, int K, int N>
__global__ __launch_bounds__(512, 2) void k_g256(const unsigned short* __restrict__ A,
                                                 const unsigned short* __restrict__ Bt,
                                                 void* __restrict__ out,
                                                 const float* __restrict__ bias,
                                                 const float* __restrict__ add){
  __shared__ char smem[131072];
  const int tid  = threadIdx.x;
  const int lane = tid & 63;
  const int w    = tid >> 6;
  const int wr   = w >> 2, wc = w & 3;
  const int nwg  = gridDim.x * gridDim.y;
  const int wgid = xcd_remap(blockIdx.y * gridDim.x + blockIdx.x, nwg);
  const long bcol = (long)(wgid % gridDim.x) * 256;
  const long brow = (long)(wgid / gridDim.x) * 256;
  const int lr = lane & 15;
  const int lk = (lane >> 4) * 16;
  const int srow  = tid >> 3;
  const int sbyte = ((tid & 7) * 16) ^ ((srow & 7) << 4);   // T2 pre-swizzled source col
  const unsigned swb = (unsigned)(w * 1024);
  const int rsw = (lr & 7) << 4;                            // T2 read-side XOR

  f32x4 acc[8][4];
  #pragma unroll
  for (int i = 0; i < 8; i++)
    #pragma unroll
    for (int j = 0; j < 4; j++){ f32x4 z = {0.f,0.f,0.f,0.f}; acc[i][j] = z; }

  const char* Ab = (const char*)(A + brow * (long)K);
  const char* Bb = (const char*)(Bt + bcol * (long)K);

  auto ST = [&](const char* g, int ldsoff, int row0, int kt){
    GLDS(g + ((long)(row0 + srow) * K + (long)kt * 64) * 2 + sbyte,
         smem + ldsoff + row0 * 128 + swb);
  };
  auto stA0 = [&](int b, int kt){ ST(Ab, b*32768, 0,  kt); ST(Ab, b*32768, 128, kt); };
  auto stA1 = [&](int b, int kt){ ST(Ab, b*32768, 64, kt); ST(Ab, b*32768, 192, kt); };
  auto stB0 = [&](int b, int kt){ ST(Bb, 65536+b*32768, 0,   kt); ST(Bb, 65536+b*32768, 64,  kt); };
  auto stB1 = [&](int b, int kt){ ST(Bb, 65536+b*32768, 128, kt); ST(Bb, 65536+b*32768, 192, kt); };

  short8 afr[4][2], bfr[2][2];
  auto RDA = [&](int b, int qm){
    #pragma unroll
    for (int mj = 0; mj < 4; mj++)
      #pragma unroll
      for (int kk = 0; kk < 2; kk++)
        afr[mj][kk] = *(const short8*)(smem + b*32768 +
            (wr*128 + (qm*4+mj)*16 + lr) * 128 + ((kk*64 + lk) ^ rsw));
  };
  auto RDB = [&](int b, int qn){
    #pragma unroll
    for (int nj = 0; nj < 2; nj++)
      #pragma unroll
      for (int kk = 0; kk < 2; kk++)
        bfr[nj][kk] = *(const short8*)(smem + 65536 + b*32768 +
            (wc*64 + (qn*2+nj)*16 + lr) * 128 + ((kk*64 + lk) ^ rsw));
  };
  auto MM = [&](int qm, int qn){
    __builtin_amdgcn_s_setprio(1);
    #pragma unroll
    for (int mj = 0; mj < 4; mj++)
      #pragma unroll
      for (int nj = 0; nj < 2; nj++)
        #pragma unroll
        for (int kk = 0; kk < 2; kk++)
          acc[qm*4+mj][qn*2+nj] =
            __builtin_amdgcn_mfma_f32_16x16x32_bf16(afr[mj][kk], bfr[nj][kk],
                                                    acc[qm*4+mj][qn*2+nj], 0, 0, 0);
    __builtin_amdgcn_s_setprio(0);
  };

  constexpr int nt    = K >> 6;
  constexpr int niter = nt >> 1;

  stA0(0, 0); stA1(0, 0); stB0(0, 0); stB1(0, 0);
  stA0(1, 1);
  VMW2;
  __builtin_amdgcn_s_barrier();

  #pragma unroll 1
  for (int i = 0; i < niter; i++){
    const int t = 2 * i;
    RDA(0,0); RDB(0,0); stA1(1, t+1);
    PH_PRE; MM(0,0); PH_END;
    RDA(0,1); stB0(1, t+1);
    PH_PRE; MM(1,0); PH_END;
    RDA(0,0); RDB(0,1); stB1(1, t+1);
    PH_PRE; MM(0,1); PH_END;
    RDA(0,1); if (t + 2 < nt) stA0(0, t+2);
    PH_PRE; MM(1,1);
    if (t + 2 < nt) { VMW2; } else { VMW0; }
    PH_END;
    RDA(1,0); RDB(1,0); if (t + 2 < nt) stA1(0, t+2);
    PH_PRE; MM(0,0); PH_END;
    RDA(1,1); if (t + 2 < nt) stB0(0, t+2);
    PH_PRE; MM(1,0); PH_END;
    RDA(1,0); RDB(1,1); if (t + 2 < nt) stB1(0, t+2);
    PH_PRE; MM(0,1); PH_END;
    RDA(1,1); if (t + 3 < nt) stA0(1, t+3);
    PH_PRE; MM(1,1);
    if (i + 1 < niter){ if (t + 3 < nt) { VMW2; } else { VMW0; } }
    PH_END;
  }

  const long rb = brow + wr * 128;
  const long cb = bcol + wc * 64;
  #pragma unroll
  for (int mi = 0; mi < 8; mi++){
    #pragma unroll
    for (int ni = 0; ni < 4; ni++){
      long rg0 = rb + mi * 16 + (lane >> 4) * 4;
      long cg  = cb + ni * 16 + lr;
      #pragma unroll
      for (int j = 0; j < 4; j++){
        long oi = (rg0 + j) * (long)N + cg;
        float v = acc[mi][ni][j];
        if (EPI == 1){
          ((unsigned short*)out)[oi] = f2bf(v);
        } else if (EPI == 3){
          v += bias[cg];
          v = 0.5f * v * (1.0f + erff(v * 0.70710678118654752f));
          ((unsigned short*)out)[oi] = f2bf(v);
        } else {
          v += bias[cg] + add[oi];
          ((float*)out)[oi] = v;
        }
      }
    }
  }
}

// ===== fused gates GEMM (8-phase) + sigmoid + gated combine + residual — R7-proven =====
__global__ __launch_bounds__(512, 2) void k_gc256(const unsigned short* __restrict__ A,
                                                  const unsigned short* __restrict__ Bt,
                                                  const float* __restrict__ gb,
                                                  const unsigned short* __restrict__ loc,
                                                  const unsigned short* __restrict__ ctx,
                                                  const float* __restrict__ x,
                                                  float* __restrict__ x2){
  __shared__ char smem[131072];
  const int tid  = threadIdx.x;
  const int lane = tid & 63;
  const int w    = tid >> 6;
  const int wr   = w >> 2, wc = w & 3;
  const int nwg  = gridDim.x * gridDim.y;
  const int wgid = xcd_remap(blockIdx.y * gridDim.x + blockIdx.x, nwg);
  const int  bcol = (wgid % gridDim.x) * 128;
  const long brow = (long)(wgid / gridDim.x) * 256;
  const int K = 512;
  const int lr = lane & 15;
  const int lk = (lane >> 4) * 16;
  const int srow  = tid >> 3;
  const int sbyte = ((tid & 7) * 16) ^ ((srow & 7) << 4);
  const unsigned swb = (unsigned)(w * 1024);
  const int rsw = (lr & 7) << 4;

  f32x4 acc[8][2][2];
  #pragma unroll
  for (int i = 0; i < 8; i++)
    #pragma unroll
    for (int j = 0; j < 2; j++)
      #pragma unroll
      for (int h = 0; h < 2; h++){ f32x4 z = {0.f,0.f,0.f,0.f}; acc[i][j][h] = z; }

  const char* Ab  = (const char*)(A + brow * (long)K);
  const char* BbL = (const char*)(Bt + (long)bcol * K);
  const char* BbG = (const char*)(Bt + (long)(512 + bcol) * K);

  auto ST = [&](const char* g, int ldsoff, int row0, int kt){
    GLDS(g + ((long)(row0 + srow) * K + (long)kt * 64) * 2 + sbyte,
         smem + ldsoff + row0 * 128 + swb);
  };
  auto stA0 = [&](int b, int kt){ ST(Ab, b*32768, 0,  kt); ST(Ab, b*32768, 128, kt); };
  auto stA1 = [&](int b, int kt){ ST(Ab, b*32768, 64, kt); ST(Ab, b*32768, 192, kt); };
  auto stBL = [&](int b, int kt){ ST(BbL, 65536+b*32768,       0, kt); ST(BbL, 65536+b*32768,       64, kt); };
  auto stBG = [&](int b, int kt){ ST(BbG, 65536+b*32768+16384, 0, kt); ST(BbG, 65536+b*32768+16384, 64, kt); };

  short8 afr[4][2], bfr[2][2];
  auto RDA = [&](int b, int qm){
    #pragma unroll
    for (int mj = 0; mj < 4; mj++)
      #pragma unroll
      for (int kk = 0; kk < 2; kk++)
        afr[mj][kk] = *(const short8*)(smem + b*32768 +
            (wr*128 + (qm*4+mj)*16 + lr) * 128 + ((kk*64 + lk) ^ rsw));
  };
  auto RDB = [&](int b, int h){
    #pragma unroll
    for (int nj = 0; nj < 2; nj++)
      #pragma unroll
      for (int kk = 0; kk < 2; kk++)
        bfr[nj][kk] = *(const short8*)(smem + 65536 + b*32768 + h*16384 +
            (wc*32 + nj*16 + lr) * 128 + ((kk*64 + lk) ^ rsw));
  };
  auto MM = [&](int qm, int h){
    __builtin_amdgcn_s_setprio(1);
    #pragma unroll
    for (int mj = 0; mj < 4; mj++)
      #pragma unroll
      for (int nj = 0; nj < 2; nj++)
        #pragma unroll
        for (int kk = 0; kk < 2; kk++)
          acc[qm*4+mj][nj][h] =
            __builtin_amdgcn_mfma_f32_16x16x32_bf16(afr[mj][kk], bfr[nj][kk],
                                                    acc[qm*4+mj][nj][h], 0, 0, 0);
    __builtin_amdgcn_s_setprio(0);
  };

  constexpr int nt = 8, niter = 4;   // K=512

  stA0(0, 0); stA1(0, 0); stBL(0, 0); stBG(0, 0);
  stA0(1, 1);
  VMW2;
  __builtin_amdgcn_s_barrier();

  #pragma unroll 1
  for (int i = 0; i < niter; i++){
    const int t = 2 * i;
    RDA(0,0); RDB(0,0); stA1(1, t+1);
    PH_PRE; MM(0,0); PH_END;
    RDA(0,1); stBL(1, t+1);
    PH_PRE; MM(1,0); PH_END;
    RDA(0,0); RDB(0,1); stBG(1, t+1);
    PH_PRE; MM(0,1); PH_END;
    RDA(0,1); if (t + 2 < nt) stA0(0, t+2);
    PH_PRE; MM(1,1);
    if (t + 2 < nt) { VMW2; } else { VMW0; }
    PH_END;
    RDA(1,0); RDB(1,0); if (t + 2 < nt) stA1(0, t+2);
    PH_PRE; MM(0,0); PH_END;
    RDA(1,1); if (t + 2 < nt) stBL(0, t+2);
    PH_PRE; MM(1,0); PH_END;
    RDA(1,0); RDB(1,1); if (t + 2 < nt) stBG(0, t+2);
    PH_PRE; MM(0,1); PH_END;
    RDA(1,1); if (t + 3 < nt) stA0(1, t+3);
    PH_PRE; MM(1,1);
    if (i + 1 < niter){ if (t + 3 < nt) { VMW2; } else { VMW0; } }
    PH_END;
  }

  const long rbase = brow + wr * 128;
  const int  cb_   = bcol + wc * 32;
  #pragma unroll
  for (int mi = 0; mi < 8; mi++){
    #pragma unroll
    for (int ni = 0; ni < 2; ni++){
      long rg0 = rbase + mi * 16 + (lane >> 4) * 4;
      int  cg  = cb_ + ni * 16 + lr;
      float bL = gb[cg], bG = gb[512 + cg];
      #pragma unroll
      for (int j = 0; j < 4; j++){
        long rg = rg0 + j;
        long oi = rg * 512 + cg;
        float vL = 1.0f / (1.0f + __expf(-(acc[mi][ni][0][j] + bL)));
        float vG = 1.0f / (1.0f + __expf(-(acc[mi][ni][1][j] + bG)));
        x2[oi] = x[oi] + vL * bfs(loc[oi]) + vG * bfs(ctx[oi]);
      }
    }
  }
}

// ---------------- launch ----------------
extern "C" void kernel_launch(void* const* d_in, const int* in_sizes, int n_in,
                              void* d_out, int out_size, void* d_ws, size_t ws_size,
                              hipStream_t stream){
  const float* x      = (const float*)d_in[0];
  const float* conv_w = (const float*)d_in[1];
  const float* conv_b = (const float*)d_in[2];
  const float* mb     = (const float*)d_in[3];
  const float* gate_w = (const float*)d_in[4];
  const float* gate_b = (const float*)d_in[5];
  const float* w1     = (const float*)d_in[6];
  const float* b1     = (const float*)d_in[7];
  const float* w2     = (const float*)d_in[8];
  const float* b2     = (const float*)d_in[9];
  const float* ln1g   = (const float*)d_in[10];
  const float* ln1b   = (const float*)d_in[11];
  const float* ln2g   = (const float*)d_in[12];
  const float* ln2b   = (const float*)d_in[13];

  char* ws = (char*)d_ws;
  const size_t MB = 1024ull * 1024ull;
  unsigned short* mb_bf = (unsigned short*)(ws + 0);
  unsigned short* mbT   = (unsigned short*)(ws + 512 * 1024);
  unsigned short* gwT   = (unsigned short*)(ws + 1 * MB);
  unsigned short* w1T   = (unsigned short*)(ws + 2 * MB);
  unsigned short* w2T   = (unsigned short*)(ws + 4 * MB);
  unsigned short* xn    = (unsigned short*)(ws + 8 * MB);   // 64MB; reused as h
  char* region = ws + 72 * MB;

  int S;
  if      (ws_size >= 264 * MB) S = 65536;
  else if (ws_size >= 120 * MB) S = 16384;
  else                          S = 4096;
  const int S2 = S / 2;
  const int NC  = NTOK / S;
  const int NC2 = NTOK / S2;

  unsigned short* loc_c = (unsigned short*)(region);
  unsigned short* ctx_c = (unsigned short*)(region + (size_t)S * 1024);
  unsigned short* sco_c = (unsigned short*)(region + (size_t)S * 2048);
  unsigned short* f1    = (unsigned short*)(region);

  // fused weight prep (1 kernel)
  k_prep<<<1728, 256, 0, stream>>>(mb, gate_w, w1, w2, mb_bf, mbT, gwT, w1T, w2T);

  // LN1 -> xn (bf16, full; wave-per-row)
  k_ln4<<<NTOK / 4, 256, 0, stream>>>(x, ln1g, ln1b, (unsigned*)xn);

  // middle phase, chunked over tokens
  for (int c = 0; c < NC; c++){
    const int base = c * S;
    const unsigned short* xnc = xn + (size_t)base * 512;
    // depthwise causal conv -> loc (8 tokens/thread)
    k_conv8<<<S / 8, 256, 0, stream>>>((const unsigned*)xn, conv_w, conv_b,
                                       (unsigned*)loc_c, base);
    // scores = xn @ mb^T (bf16)
    k_g256<1, 512, 512><<<dim3(2, S / 256), 512, 0, stream>>>(xnc, mb_bf, sco_c,
                                                              nullptr, nullptr);
    // softmax rows in-place (wave-per-row)
    k_softmax4<<<S / 4, 256, 0, stream>>>((unsigned*)sco_c);
    // ctx = weights @ mb (bf16)
    k_g256<1, 512, 512><<<dim3(2, S / 256), 512, 0, stream>>>(sco_c, mbT, ctx_c,
                                                              nullptr, nullptr);
    // gates GEMM (8-phase) + sigmoid + combine + residual -> x2 (f32, into d_out)
    k_gc256<<<dim3(4, S / 256), 512, 0, stream>>>(xnc, gwT, gate_b,
                                                  loc_c, ctx_c,
                                                  x + (size_t)base * 512,
                                                  (float*)d_out + (size_t)base * 512);
  }

  // LN2: h = LN(x2) (bf16, reuse xn buffer; wave-per-row)
  k_ln4<<<NTOK / 4, 256, 0, stream>>>((const float*)d_out, ln2g, ln2b, (unsigned*)xn);

  // FFN, chunked
  for (int c = 0; c < NC2; c++){
    const int base = c * S2;
    // f1 = gelu(h @ w1 + b1) (bf16)
    k_g256<3, 512, 2048><<<dim3(8, S2 / 256), 512, 0, stream>>>(xn + (size_t)base * 512,
                                                                w1T, f1, b1, nullptr);
    // out = x2 + f1 @ w2 + b2 (f32, in-place per-element on d_out)
    k_g256<4, 2048, 512><<<dim3(2, S2 / 256), 512, 0, stream>>>(f1, w2T,
                                                                (float*)d_out + (size_t)base * 512,
                                                                b2,
                                                                (const float*)d_out + (size_t)base * 512);
  }
}